// Round 2
// baseline (444.552 us; speedup 1.0000x reference)
//
#include <hip/hip_runtime.h>
#include <stdint.h>

#define B_ 32
#define F_ 8
#define H_ 224
#define W_ 224
#define NPIX (H_ * W_)          // 50176
#define NFRAMES (B_ * F_)       // 256
#define CHSTRIDE (F_ * H_ * W_) // 401408
#define NT 1024
#define NW 16

// ---------------- Kernel 1: gray quantization ----------------
__device__ __forceinline__ uint8_t quant1(float s) {
    float gr = s / 3.0f;
    float v = floorf(gr * 255.0f);
    v = fminf(fmaxf(v, 0.0f), 255.0f);
    return (uint8_t)(int)v;
}

__global__ __launch_bounds__(256) void k_gray(const float* __restrict__ x,
                                              uchar4* __restrict__ g4, int nq4) {
    int t = blockIdx.x * blockDim.x + threadIdx.x;
    if (t >= nq4) return;
    int q = t * 4;
    int b = q / CHSTRIDE;
    int rem = q - b * CHSTRIDE;
    const float4* p0 = reinterpret_cast<const float4*>(x + (size_t)(b * 3 + 0) * CHSTRIDE + rem);
    const float4* p1 = reinterpret_cast<const float4*>(x + (size_t)(b * 3 + 1) * CHSTRIDE + rem);
    const float4* p2 = reinterpret_cast<const float4*>(x + (size_t)(b * 3 + 2) * CHSTRIDE + rem);
    float4 a = *p0, bb = *p1, c = *p2;
    uchar4 o;
    o.x = quant1(a.x + bb.x + c.x);
    o.y = quant1(a.y + bb.y + c.y);
    o.z = quant1(a.z + bb.z + c.z);
    o.w = quant1(a.w + bb.w + c.w);
    g4[t] = o;
}

// ---------------- pair pass: histogram atomics only ----------------
// Wave handles row r; lanes 0..55 each cover 4 consecutive columns via one
// dword load per row. Shifted-column B operand built with shfl + funnel shift.
template<int DR, int DC>
__device__ __forceinline__ void pair_pass(const uint8_t* __restrict__ gf,
                                          uint32_t* hist, int wave, int lane) {
    constexpr int nr = H_ - DR;
    if (lane < 56) {
        for (int r = wave; r < nr; r += NW) {
            const uint32_t* rowA = reinterpret_cast<const uint32_t*>(gf + r * W_);
            uint32_t A = rowA[lane];
            uint32_t B;
            if (DR) {
                const uint32_t* rowB = reinterpret_cast<const uint32_t*>(gf + (r + DR) * W_);
                B = rowB[lane];
            } else {
                B = A;
            }
            uint32_t Bv;
            if (DC == 1) {
                uint32_t Bn = __shfl_down(B, 1, 64);
                Bv = (B >> 8) | (Bn << 24);          // bytes = cols 4l+1 .. 4l+4
            } else if (DC == -1) {
                uint32_t Bp = __shfl_up(B, 1, 64);
                Bv = (B << 8) | (Bp >> 24);          // bytes = cols 4l-1 .. 4l+2
            } else {
                Bv = B;
            }
            int cb = lane * 4;
            #pragma unroll
            for (int k = 0; k < 4; ++k) {
                bool valid = (DC == 1) ? (cb + k < W_ - 1)
                           : (DC == -1) ? (cb + k >= 1)
                           : true;
                if (valid) {
                    uint32_t a = (A  >> (8 * k)) & 0xffu;
                    uint32_t b = (Bv >> (8 * k)) & 0xffu;
                    uint32_t idx = (a << 8) | b;      // h[a][b], reference order
                    atomicAdd(&hist[idx >> 1], 1u << ((idx & 1) << 4));
                }
            }
        }
    }
}

// ---------------- stats pass: con/dis/hom/asm from the histogram ----------------
// 2x2 bin tiles: i0=2u, j0=2*((u+s)&127). One u32 word read per row-of-tile and
// per transpose-row -> 1 LDS read per (i,j) entry, transposes included.
// Weights depend only on the diagonal s (wave-uniform) -> hoisted.
__device__ __forceinline__ void stats_pass(const uint32_t* hist, int wave, int lane,
                                           double inv2np,
                                           double& conD, double& disD,
                                           double& homD, double& asmD) {
    unsigned long long S = 0ull, conU = 0ull;
    uint32_t disU = 0u;
    float homF = 0.0f;
    #pragma unroll
    for (int q = 0; q < 8; ++q) {
        int s = wave + NW * q;                 // 0..127
        int t2 = 2 * s;
        int dAn = t2, dBn = t2 + 1, dCn = (t2 >= 1) ? (t2 - 1) : (1 - t2);
        int dAw = 256 - t2, dBw = 255 - t2, dCw = 257 - t2;
        int d2An = dAn * dAn, d2Bn = dBn * dBn, d2Cn = dCn * dCn;
        int d2Aw = dAw * dAw, d2Bw = dBw * dBw, d2Cw = dCw * dCw;
        float hAn = 1.0f / (1.0f + (float)d2An);
        float hBn = 1.0f / (1.0f + (float)d2Bn);
        float hCn = 1.0f / (1.0f + (float)d2Cn);
        float hAw = 1.0f / (1.0f + (float)d2Aw);
        float hBw = 1.0f / (1.0f + (float)d2Bw);
        float hCw = 1.0f / (1.0f + (float)d2Cw);
        #pragma unroll
        for (int p = 0; p < 2; ++p) {
            int u = lane + 64 * p;             // i0/2, 0..127
            int uw = u + s;
            bool wrap = uw >= 128;
            int j0h = uw & 127;                // j0/2
            int ai = (u << 8) + j0h;           // word: row i0, cols (j0, j0+1)
            int aj = (j0h << 8) + u;           // word: row j0, cols (i0, i0+1)
            uint32_t wi0 = hist[ai], wi1 = hist[ai + 128];
            uint32_t wj0 = hist[aj], wj1 = hist[aj + 128];
            uint32_t v00 = (wi0 & 0xffffu) + (wj0 & 0xffffu);   // (i0  , j0  )
            uint32_t v01 = (wi0 >> 16)     + (wj1 & 0xffffu);   // (i0  , j0+1)
            uint32_t v10 = (wi1 & 0xffffu) + (wj0 >> 16);       // (i0+1, j0  )
            uint32_t v11 = (wi1 >> 16)     + (wj1 >> 16);       // (i0+1, j0+1)
            S += (unsigned long long)v00 * v00;
            S += (unsigned long long)v01 * v01;
            S += (unsigned long long)v10 * v10;
            S += (unsigned long long)v11 * v11;
            uint32_t vA  = v00 + v11;                            // share |d|
            uint32_t d2A = wrap ? (uint32_t)d2Aw : (uint32_t)d2An;
            uint32_t d2B = wrap ? (uint32_t)d2Bw : (uint32_t)d2Bn;
            uint32_t d2C = wrap ? (uint32_t)d2Cw : (uint32_t)d2Cn;
            uint32_t dA  = wrap ? (uint32_t)dAw  : (uint32_t)dAn;
            uint32_t dB  = wrap ? (uint32_t)dBw  : (uint32_t)dBn;
            uint32_t dC  = wrap ? (uint32_t)dCw  : (uint32_t)dCn;
            float    hA  = wrap ? hAw : hAn;
            float    hB  = wrap ? hBw : hBn;
            float    hC  = wrap ? hCw : hCn;
            conU += (unsigned long long)vA  * d2A
                  + (unsigned long long)v01 * d2B
                  + (unsigned long long)v10 * d2C;
            disU += vA * dA + v01 * dB + v10 * dC;
            homF += (float)vA * hA + (float)v01 * hB + (float)v10 * hC;
        }
    }
    conD += (double)conU * inv2np;
    disD += (double)disU * inv2np;
    homD += (double)homF * inv2np;
    asmD += (double)S * (inv2np * inv2np);     // S / (4 np^2)
}

// ---------------- Kernel 2: one frame per block ----------------
__global__ __launch_bounds__(NT) void k_glcm(const uint8_t* __restrict__ g,
                                             float* __restrict__ out) {
    __shared__ uint32_t hist[32768];   // 128 KB: 256x256 u16 counts, packed 2/word
    __shared__ double red[NW * 8];

    const int frame = blockIdx.x;
    const uint8_t* __restrict__ gf = g + (size_t)frame * NPIX;
    const int tid = threadIdx.x, lane = tid & 63, wave = tid >> 6;

    // ---- std partials (dword loads, exact integer sums) ----
    uint32_t s1 = 0, s2 = 0;
    const uint32_t* g32 = reinterpret_cast<const uint32_t*>(gf);
    for (int i = tid; i < NPIX / 4; i += NT) {
        uint32_t w = g32[i];
        #pragma unroll
        for (int k = 0; k < 4; ++k) {
            uint32_t v = (w >> (8 * k)) & 0xffu;
            s1 += v;
            s2 += v * v;
        }
    }

    double conD = 0.0, disD = 0.0, homD = 0.0, asmD = 0.0;
    uint4* h4 = reinterpret_cast<uint4*>(hist);

    // ---- offset (0,1), np = 224*223 = 49952 ----
    for (int i = tid; i < 8192; i += NT) h4[i] = make_uint4(0u, 0u, 0u, 0u);
    __syncthreads();
    pair_pass<0, 1>(gf, hist, wave, lane);
    __syncthreads();
    stats_pass(hist, wave, lane, 1.0 / (2.0 * 49952.0), conD, disD, homD, asmD);
    __syncthreads();

    // ---- offset (1,1), np = 223*223 = 49729 ----
    for (int i = tid; i < 8192; i += NT) h4[i] = make_uint4(0u, 0u, 0u, 0u);
    __syncthreads();
    pair_pass<1, 1>(gf, hist, wave, lane);
    __syncthreads();
    stats_pass(hist, wave, lane, 1.0 / (2.0 * 49729.0), conD, disD, homD, asmD);
    __syncthreads();

    // ---- offset (1,0), np = 223*224 = 49952 ----
    for (int i = tid; i < 8192; i += NT) h4[i] = make_uint4(0u, 0u, 0u, 0u);
    __syncthreads();
    pair_pass<1, 0>(gf, hist, wave, lane);
    __syncthreads();
    stats_pass(hist, wave, lane, 1.0 / (2.0 * 49952.0), conD, disD, homD, asmD);
    __syncthreads();

    // ---- offset (1,-1), np = 223*223 = 49729 ----
    for (int i = tid; i < 8192; i += NT) h4[i] = make_uint4(0u, 0u, 0u, 0u);
    __syncthreads();
    pair_pass<1, -1>(gf, hist, wave, lane);
    __syncthreads();
    stats_pass(hist, wave, lane, 1.0 / (2.0 * 49729.0), conD, disD, homD, asmD);
    __syncthreads();

    // ---- fused reduction of 6 doubles ----
    double vals[6] = {(double)s1, (double)s2, conD, disD, homD, asmD};
    #pragma unroll
    for (int off = 32; off; off >>= 1) {
        #pragma unroll
        for (int i = 0; i < 6; ++i) vals[i] += __shfl_down(vals[i], off, 64);
    }
    if (lane == 0) {
        #pragma unroll
        for (int i = 0; i < 6; ++i) red[wave * 8 + i] = vals[i];
    }
    __syncthreads();
    if (tid == 0) {
        double acc[6];
        #pragma unroll
        for (int i = 0; i < 6; ++i) {
            double t = red[i];
            for (int w = 1; w < NW; ++w) t += red[w * 8 + i];
            acc[i] = t;
        }
        double N = (double)NPIX;
        double mean = acc[0] / N;
        double var = acc[1] / N - mean * mean;
        if (var < 0.0) var = 0.0;
        double sd = sqrt(var);
        double con = acc[2] * 0.25;
        double dis = acc[3] * 0.25;
        double hom = acc[4] * 0.25;
        double as  = acc[5] * 0.25;
        float* op = out + frame * 6;
        op[0] = (float)sd;
        op[1] = (float)con;
        op[2] = (float)dis;
        op[3] = (float)hom;
        op[4] = (float)as;
        op[5] = (float)sqrt(as);
    }
}

extern "C" void kernel_launch(void* const* d_in, const int* in_sizes, int n_in,
                              void* d_out, int out_size, void* d_ws, size_t ws_size,
                              hipStream_t stream) {
    const float* x = (const float*)d_in[0];
    float* out = (float*)d_out;
    uint8_t* g = (uint8_t*)d_ws;                // 12,845,056 bytes

    const int npix_total = B_ * F_ * H_ * W_;   // 12,845,056
    const int nq4 = npix_total / 4;             // 3,211,264
    const int blocks1 = (nq4 + 255) / 256;      // 12,544

    k_gray<<<blocks1, 256, 0, stream>>>(x, (uchar4*)g, nq4);
    k_glcm<<<NFRAMES, 1024, 0, stream>>>(g, out);
}

// Round 3
// 81.164 us; speedup vs baseline: 5.4772x; 5.4772x over previous
//
#include <hip/hip_runtime.h>
#include <stdint.h>

#define B_ 32
#define F_ 8
#define H_ 224
#define W_ 224
#define NPIX (H_ * W_)          // 50176
#define NFRAMES (B_ * F_)       // 256
#define CHSTRIDE (F_ * H_ * W_) // 401408
#define NT 1024
#define NW 16

// ---------------- Kernel 1: gray quantization ----------------
__device__ __forceinline__ uint8_t quant1(float s) {
    float gr = s / 3.0f;
    float v = floorf(gr * 255.0f);
    v = fminf(fmaxf(v, 0.0f), 255.0f);
    return (uint8_t)(int)v;
}

__global__ __launch_bounds__(256) void k_gray(const float* __restrict__ x,
                                              uchar4* __restrict__ g4, int nq4) {
    int t = blockIdx.x * blockDim.x + threadIdx.x;
    if (t >= nq4) return;
    int q = t * 4;
    int b = q / CHSTRIDE;
    int rem = q - b * CHSTRIDE;
    const float4* p0 = reinterpret_cast<const float4*>(x + (size_t)(b * 3 + 0) * CHSTRIDE + rem);
    const float4* p1 = reinterpret_cast<const float4*>(x + (size_t)(b * 3 + 1) * CHSTRIDE + rem);
    const float4* p2 = reinterpret_cast<const float4*>(x + (size_t)(b * 3 + 2) * CHSTRIDE + rem);
    float4 a = *p0, bb = *p1, c = *p2;
    uchar4 o;
    o.x = quant1(a.x + bb.x + c.x);
    o.y = quant1(a.y + bb.y + c.y);
    o.z = quant1(a.z + bb.z + c.z);
    o.w = quant1(a.w + bb.w + c.w);
    g4[t] = o;
}

// ---------------- pair pass: histogram atomics only ----------------
// Wave handles row r; lanes 0..55 each cover 4 consecutive columns via one
// dword load per row. Shifted-column B operand built with shfl + funnel shift.
template<int DR, int DC>
__device__ __forceinline__ void pair_pass(const uint8_t* __restrict__ gf,
                                          uint32_t* hist, int wave, int lane) {
    constexpr int nr = H_ - DR;
    if (lane < 56) {
        for (int r = wave; r < nr; r += NW) {
            const uint32_t* rowA = reinterpret_cast<const uint32_t*>(gf + r * W_);
            uint32_t A = rowA[lane];
            uint32_t B;
            if (DR) {
                const uint32_t* rowB = reinterpret_cast<const uint32_t*>(gf + (r + DR) * W_);
                B = rowB[lane];
            } else {
                B = A;
            }
            uint32_t Bv;
            if (DC == 1) {
                uint32_t Bn = __shfl_down(B, 1, 64);
                Bv = (B >> 8) | (Bn << 24);          // bytes = cols 4l+1 .. 4l+4
            } else if (DC == -1) {
                uint32_t Bp = __shfl_up(B, 1, 64);
                Bv = (B << 8) | (Bp >> 24);          // bytes = cols 4l-1 .. 4l+2
            } else {
                Bv = B;
            }
            int cb = lane * 4;
            #pragma unroll
            for (int k = 0; k < 4; ++k) {
                bool valid = (DC == 1) ? (cb + k < W_ - 1)
                           : (DC == -1) ? (cb + k >= 1)
                           : true;
                if (valid) {
                    uint32_t a = (A  >> (8 * k)) & 0xffu;
                    uint32_t b = (Bv >> (8 * k)) & 0xffu;
                    uint32_t idx = (a << 8) | b;      // h[a][b], reference order
                    atomicAdd(&hist[idx >> 1], 1u << ((idx & 1) << 4));
                }
            }
        }
    }
}

// ---------------- stats pass: con/dis/hom/asm from the histogram ----------------
// Unit (i2, jh) covers the 2x2 bin tile (rows 2*i2..+1, cols 2*jh..+1) AND its
// transpose tile via 4 packed-u16 word reads -> 1 LDS read per entry.
// Diagonal lane mapping: jh = (i2 + s) & 127 -> own-read bank = (lane+s)&31,
// transpose-read bank = lane&31: free 2-way alias, no conflicts.
// Weights computed inline from d = 2*(i2 - jh): register-lean (no spills).
__device__ __forceinline__ void stats_pass(const uint32_t* hist, int wave, int lane,
                                           double inv2np,
                                           double& conD, double& disD,
                                           double& homD, double& asmD) {
    unsigned long long S = 0ull, conU = 0ull;
    uint32_t disU = 0u;
    float homF = 0.0f;
    #pragma unroll 2
    for (int q = 0; q < 8; ++q) {
        int s = wave + NW * q;                 // diagonal 0..127
        #pragma unroll
        for (int p = 0; p < 2; ++p) {
            int i2 = lane + (p << 6);          // 0..127
            int jh = (i2 + s) & 127;
            int a = (i2 << 8) + jh;
            int b = (jh << 8) + i2;
            uint32_t A0 = hist[a];             // h[2i2  ][2jh], h[2i2  ][2jh+1]
            uint32_t A1 = hist[a + 128];       // h[2i2+1][2jh], h[2i2+1][2jh+1]
            uint32_t B0 = hist[b];             // h[2jh  ][2i2], h[2jh  ][2i2+1]
            uint32_t B1 = hist[b + 128];       // h[2jh+1][2i2], h[2jh+1][2i2+1]
            uint32_t v00 = (A0 & 0xffffu) + (B0 & 0xffffu);
            uint32_t v01 = (A0 >> 16)     + (B1 & 0xffffu);
            uint32_t v10 = (A1 & 0xffffu) + (B0 >> 16);
            uint32_t v11 = (A1 >> 16)     + (B1 >> 16);
            S += (unsigned long long)v00 * v00 + (unsigned long long)v01 * v01
               + (unsigned long long)v10 * v10 + (unsigned long long)v11 * v11;
            int d = 2 * (i2 - jh);             // i0 - j0 (even)
            int dB = d - 1, dC = d + 1;
            uint32_t d2A = (uint32_t)(d * d);
            uint32_t d2B = (uint32_t)(dB * dB);
            uint32_t d2C = (uint32_t)(dC * dC);
            uint32_t vA = v00 + v11;           // entries sharing weight of d
            conU += (unsigned long long)vA  * d2A
                  + (unsigned long long)v01 * d2B
                  + (unsigned long long)v10 * d2C;
            uint32_t adA = (uint32_t)(d  < 0 ? -d  : d);
            uint32_t adB = (uint32_t)(dB < 0 ? -dB : dB);
            uint32_t adC = (uint32_t)(dC < 0 ? -dC : dC);
            disU += vA * adA + v01 * adB + v10 * adC;
            homF += (float)vA  * __builtin_amdgcn_rcpf(1.0f + (float)d2A)
                  + (float)v01 * __builtin_amdgcn_rcpf(1.0f + (float)d2B)
                  + (float)v10 * __builtin_amdgcn_rcpf(1.0f + (float)d2C);
        }
    }
    conD += (double)conU * inv2np;
    disD += (double)disU * inv2np;
    homD += (double)homF * inv2np;
    asmD += (double)S * (inv2np * inv2np);     // S / (4 np^2)
}

// ---------------- Kernel 2: one frame per block ----------------
__global__ __launch_bounds__(NT, 4) void k_glcm(const uint8_t* __restrict__ g,
                                                float* __restrict__ out) {
    __shared__ uint32_t hist[32768];   // 128 KB: 256x256 u16 counts, packed 2/word
    __shared__ double red[NW * 8];

    const int frame = blockIdx.x;
    const uint8_t* __restrict__ gf = g + (size_t)frame * NPIX;
    const int tid = threadIdx.x, lane = tid & 63, wave = tid >> 6;

    // ---- std partials (dword loads, exact integer sums) ----
    uint32_t s1 = 0, s2 = 0;
    const uint32_t* g32 = reinterpret_cast<const uint32_t*>(gf);
    for (int i = tid; i < NPIX / 4; i += NT) {
        uint32_t w = g32[i];
        #pragma unroll
        for (int k = 0; k < 4; ++k) {
            uint32_t v = (w >> (8 * k)) & 0xffu;
            s1 += v;
            s2 += v * v;
        }
    }

    double conD = 0.0, disD = 0.0, homD = 0.0, asmD = 0.0;
    uint4* h4 = reinterpret_cast<uint4*>(hist);

    // ---- offset (0,1), np = 224*223 = 49952 ----
    for (int i = tid; i < 8192; i += NT) h4[i] = make_uint4(0u, 0u, 0u, 0u);
    __syncthreads();
    pair_pass<0, 1>(gf, hist, wave, lane);
    __syncthreads();
    stats_pass(hist, wave, lane, 1.0 / (2.0 * 49952.0), conD, disD, homD, asmD);
    __syncthreads();

    // ---- offset (1,1), np = 223*223 = 49729 ----
    for (int i = tid; i < 8192; i += NT) h4[i] = make_uint4(0u, 0u, 0u, 0u);
    __syncthreads();
    pair_pass<1, 1>(gf, hist, wave, lane);
    __syncthreads();
    stats_pass(hist, wave, lane, 1.0 / (2.0 * 49729.0), conD, disD, homD, asmD);
    __syncthreads();

    // ---- offset (1,0), np = 223*224 = 49952 ----
    for (int i = tid; i < 8192; i += NT) h4[i] = make_uint4(0u, 0u, 0u, 0u);
    __syncthreads();
    pair_pass<1, 0>(gf, hist, wave, lane);
    __syncthreads();
    stats_pass(hist, wave, lane, 1.0 / (2.0 * 49952.0), conD, disD, homD, asmD);
    __syncthreads();

    // ---- offset (1,-1), np = 223*223 = 49729 ----
    for (int i = tid; i < 8192; i += NT) h4[i] = make_uint4(0u, 0u, 0u, 0u);
    __syncthreads();
    pair_pass<1, -1>(gf, hist, wave, lane);
    __syncthreads();
    stats_pass(hist, wave, lane, 1.0 / (2.0 * 49729.0), conD, disD, homD, asmD);
    __syncthreads();

    // ---- fused reduction of 6 doubles ----
    double vals[6] = {(double)s1, (double)s2, conD, disD, homD, asmD};
    #pragma unroll
    for (int off = 32; off; off >>= 1) {
        #pragma unroll
        for (int i = 0; i < 6; ++i) vals[i] += __shfl_down(vals[i], off, 64);
    }
    if (lane == 0) {
        #pragma unroll
        for (int i = 0; i < 6; ++i) red[wave * 8 + i] = vals[i];
    }
    __syncthreads();
    if (tid == 0) {
        double acc[6];
        #pragma unroll
        for (int i = 0; i < 6; ++i) {
            double t = red[i];
            for (int w = 1; w < NW; ++w) t += red[w * 8 + i];
            acc[i] = t;
        }
        double N = (double)NPIX;
        double mean = acc[0] / N;
        double var = acc[1] / N - mean * mean;
        if (var < 0.0) var = 0.0;
        double sd = sqrt(var);
        double con = acc[2] * 0.25;
        double dis = acc[3] * 0.25;
        double hom = acc[4] * 0.25;
        double as  = acc[5] * 0.25;
        float* op = out + frame * 6;
        op[0] = (float)sd;
        op[1] = (float)con;
        op[2] = (float)dis;
        op[3] = (float)hom;
        op[4] = (float)as;
        op[5] = (float)sqrt(as);
    }
}

extern "C" void kernel_launch(void* const* d_in, const int* in_sizes, int n_in,
                              void* d_out, int out_size, void* d_ws, size_t ws_size,
                              hipStream_t stream) {
    const float* x = (const float*)d_in[0];
    float* out = (float*)d_out;
    uint8_t* g = (uint8_t*)d_ws;                // 12,845,056 bytes

    const int npix_total = B_ * F_ * H_ * W_;   // 12,845,056
    const int nq4 = npix_total / 4;             // 3,211,264
    const int blocks1 = (nq4 + 255) / 256;      // 12,544

    k_gray<<<blocks1, 256, 0, stream>>>(x, (uchar4*)g, nq4);
    k_glcm<<<NFRAMES, 1024, 0, stream>>>(g, out);
}